// Round 10
// baseline (375.035 us; speedup 1.0000x reference)
//
#include <hip/hip_runtime.h>
#include <stdint.h>
#include <math.h>

// Problem constants
#define NN   20000
#define EE   320000
#define HH   128
#define MSTR 136            // h1/mij LDS row stride (u16)

typedef __attribute__((ext_vector_type(8)))  short          bf16x8;
typedef __attribute__((ext_vector_type(4)))  float          f32x4;
typedef __attribute__((ext_vector_type(16))) float          f32x16;
typedef __attribute__((ext_vector_type(8)))  unsigned short u16x8;
typedef unsigned short u16;

// fp32 -> bf16 round-to-nearest-even
__device__ __forceinline__ u16 f2b(float f) {
  union { float f; unsigned int u; } v; v.f = f;
  return (u16)((v.u + 0x7fffu + ((v.u >> 16) & 1u)) >> 16);
}
__device__ __forceinline__ float b2f(unsigned int x) {
  union { float f; unsigned int u; } v; v.u = x << 16;
  return v.f;
}
__device__ __forceinline__ bf16x8 cvt8(float4 a, float4 b) {
  bf16x8 r;
  r[0] = (short)f2b(a.x); r[1] = (short)f2b(a.y);
  r[2] = (short)f2b(a.z); r[3] = (short)f2b(a.w);
  r[4] = (short)f2b(b.x); r[5] = (short)f2b(b.y);
  r[6] = (short)f2b(b.z); r[7] = (short)f2b(b.w);
  return r;
}

// packed bf16x2 atomic add (CDNA4 global_atomic_pk_add_bf16), fire-and-forget
__device__ __forceinline__ void pk_atomic_bf16(u16* addr, unsigned int data) {
  asm volatile("global_atomic_pk_add_bf16 %0, %1, off"
               :
               : "v"((unsigned long long)(uintptr_t)addr), "v"(data)
               : "memory");
}

// ---------------------------------------------------------------------------
// prep: (a) zero mi+dx, (b) h -> bf16 (hb), (c) pack weights to bf16.
// 32-style (edge GEMMs, mfma 32x32x16): n = nt*32+(l&31), k = kc*16+(l>>5)*8+j
// 16-style (node GEMMs, mfma 16x16x32): n = nt*16+(l&15), k = kc*32+(l>>4)*8+j
// ew1 K-rows permuted to feat order (hi | hj | attr+rbf | pad).
// ---------------------------------------------------------------------------
__global__ void prep_kernel(const float* __restrict__ h,
                            const float* __restrict__ ew1, const float* __restrict__ ew2,
                            const float* __restrict__ xw1, const float* __restrict__ nw1,
                            const float* __restrict__ nw2,
                            u16* __restrict__ ew1c, u16* __restrict__ ew2c,
                            u16* __restrict__ xw1c, u16* __restrict__ nw1c,
                            u16* __restrict__ nw2c, float4* __restrict__ zbase,
                            u16* __restrict__ hb) {
  int idx = blockIdx.x * 256 + threadIdx.x;

  // zero mi (bf16, 5120000 B) + dx (240000 B) = 335000 float4s
  float4 z4 = {0.f, 0.f, 0.f, 0.f};
  #pragma unroll
  for (int i = 0; i < 3; ++i) {
    int j = idx + i * 122880;
    if (j < 335000) zbase[j] = z4;
  }
  // h -> bf16: 2,560,000 elems = 320,000 chunks of 8
  #pragma unroll
  for (int i = 0; i < 3; ++i) {
    int c = idx + i * 122880;
    if (c < 320000) {
      float4 a = *(const float4*)&h[(size_t)c * 8];
      float4 b = *(const float4*)&h[(size_t)c * 8 + 4];
      *(bf16x8*)&hb[(size_t)c * 8] = cvt8(a, b);
    }
  }

  int i2, style;
  u16* dst;
  const float* src;
  if (idx < 40960)       { i2 = idx;          dst = ew1c; src = ew1; style = 1; }
  else if (idx < 57344)  { i2 = idx - 40960;  dst = ew2c; src = ew2; style = 1; }
  else if (idx < 73728)  { i2 = idx - 57344;  dst = xw1c; src = xw1; style = 1; }
  else if (idx < 106496) { i2 = idx - 73728;  dst = nw1c; src = nw1; style = 0; }
  else if (idx < 122880) { i2 = idx - 106496; dst = nw2c; src = nw2; style = 0; }
  else return;

  int n, k;
  if (style) {
    int kc = i2 >> 11, rem = i2 & 2047, nt = rem >> 9, rem2 = rem & 511;
    int l = rem2 >> 3, j = rem2 & 7;
    n = nt * 32 + (l & 31);
    k = kc * 16 + (l >> 5) * 8 + j;
  } else {
    int kc = i2 >> 12, rem = i2 & 4095, nt = rem >> 9, rem2 = rem & 511;
    int l = rem2 >> 3, j = rem2 & 7;
    n = nt * 16 + (l & 15);
    k = kc * 32 + (l >> 4) * 8 + j;
  }
  float v;
  if (dst == ew1c) {
    if (k < 256)      v = src[(k + 48) * HH + n];   // hi|hj block
    else if (k < 304) v = src[(k - 256) * HH + n];  // attr|rbf block
    else              v = 0.0f;                     // pad (kc 19, unused)
  } else {
    v = src[k * HH + n];
  }
  dst[i2] = f2b(v);
}

// ---------------------------------------------------------------------------
// edge_prep: per-edge marshalling moved out of the hot kernel.
// Computes rel_x + |rel_x| -> relx4[e], and the bf16 feat tail
// tail[e][48] = [attr(28) | rbf(20)].  1 thread/edge, EE = 1250*256 exactly.
// ---------------------------------------------------------------------------
__global__ void edge_prep_kernel(const float* __restrict__ x,
                                 const float* __restrict__ edge_attr,
                                 const int* __restrict__ edge_index,
                                 float4* __restrict__ relx4,
                                 u16* __restrict__ tail) {
  int e = blockIdx.x * 256 + threadIdx.x;
  int d = edge_index[e];
  int s = edge_index[EE + e];
  float rx = x[d * 3 + 0] - x[s * 3 + 0];
  float ry = x[d * 3 + 1] - x[s * 3 + 1];
  float rz = x[d * 3 + 2] - x[s * 3 + 2];
  float nrm = sqrtf(rx * rx + ry * ry + rz * rz);
  float4 r4 = {rx, ry, rz, nrm};
  relx4[e] = r4;

  const float* ap = edge_attr + (size_t)e * 28;
  float4 a0 = *(const float4*)&ap[0],  a1 = *(const float4*)&ap[4];
  float4 a2 = *(const float4*)&ap[8],  a3 = *(const float4*)&ap[12];
  float4 a4 = *(const float4*)&ap[16], a5 = *(const float4*)&ap[20];
  float4 a6 = *(const float4*)&ap[24];

  const float step  = 100.0f / 19.0f;
  const float coeff = -0.5f / (step * step);
  float rb[20];
  #pragma unroll
  for (int j = 0; j < 20; ++j) {
    float dd = nrm - (float)j * step;
    rb[j] = __expf(coeff * dd * dd);
  }

  u16* tp = tail + (size_t)e * 48;
  *(bf16x8*)&tp[0]  = cvt8(a0, a1);
  *(bf16x8*)&tp[8]  = cvt8(a2, a3);
  *(bf16x8*)&tp[16] = cvt8(a4, a5);
  {
    float4 b0 = {a6.x, a6.y, a6.z, a6.w};
    float4 b1 = {rb[0], rb[1], rb[2], rb[3]};
    *(bf16x8*)&tp[24] = cvt8(b0, b1);
    float4 b2 = {rb[4], rb[5], rb[6], rb[7]};
    float4 b3 = {rb[8], rb[9], rb[10], rb[11]};
    *(bf16x8*)&tp[32] = cvt8(b2, b3);
    float4 b4 = {rb[12], rb[13], rb[14], rb[15]};
    float4 b5 = {rb[16], rb[17], rb[18], rb[19]};
    *(bf16x8*)&tp[40] = cvt8(b4, b5);
  }
}

// ---------------------------------------------------------------------------
// edge kernel v10: 128 edges/block, 4 waves, wave owns 32 rows x 128 cols.
// All inputs pre-marshalled to bf16 (hb, tail) -> A fragments are direct
// 16B loads, zero cvt VALU in the hot loop. mfma 32x32x16, one barrier,
// atomics last. bounds(256,3): no clamp (needs ~148 unified regs).
// ---------------------------------------------------------------------------
__global__ __launch_bounds__(256, 3) void edge_kernel(
    const u16* __restrict__ hb,
    const u16* __restrict__ ew1c, const float* __restrict__ eb1,
    const u16* __restrict__ ew2c, const float* __restrict__ eb2,
    const float* __restrict__ inf_w, const float* __restrict__ inf_b,
    const u16* __restrict__ xw1c, const float* __restrict__ xb1,
    const float* __restrict__ xw2, const float* __restrict__ xb2,
    const int* __restrict__ edge_index,
    const float4* __restrict__ relx4, const u16* __restrict__ tail,
    u16* __restrict__ mi, float* __restrict__ dx) {
  __shared__ u16 h1_s[128 * MSTR];     // 34816 B: GEMM1 out, then mij overlay
  __shared__ float4 relx_s[128];       //  2048 B
  __shared__ int dst_s[128];           //   512 B
  __shared__ int src_s[128];           //   512 B

  const int t   = threadIdx.x;
  const int w   = t >> 6;
  const int l   = t & 63;
  const int l31 = l & 31;
  const int hh  = l >> 5;              // k-half
  const int e0  = blockIdx.x * 128;
  const int myrow = w * 32 + l31;      // local row 0..127

  // ---- phase A: indices + rel_x (precomputed; the only barrier) ----
  if (t < 128) {
    dst_s[t] = edge_index[e0 + t];
    src_s[t] = edge_index[EE + e0 + t];
    relx_s[t] = relx4[e0 + t];
  }
  __syncthreads();

  const int dstv = dst_s[myrow];
  const int srcv = src_s[myrow];

  f32x16 acc[4];
  #pragma unroll
  for (int nt = 0; nt < 4; ++nt)
    #pragma unroll
    for (int i = 0; i < 16; ++i) acc[nt][i] = 0.f;

  // ---- GEMM1 phase hi (feat k 0..127 = hb[dst], direct bf16 loads) ----
  {
    const u16* hp = hb + (size_t)dstv * HH;
    bf16x8 af[8];
    #pragma unroll
    for (int kc = 0; kc < 8; ++kc)
      af[kc] = *(const bf16x8*)&hp[kc * 16 + hh * 8];
    #pragma unroll
    for (int kc = 0; kc < 8; ++kc) {
      const u16* bp = ew1c + (kc * 4) * 512 + l * 8;
      #pragma unroll
      for (int nt = 0; nt < 4; ++nt) {
        bf16x8 b = *(const bf16x8*)(bp + nt * 512);
        acc[nt] = __builtin_amdgcn_mfma_f32_32x32x16_bf16(af[kc], b, acc[nt], 0, 0, 0);
      }
    }
  }
  // ---- GEMM1 phase hj (feat k 128..255 = hb[src]) ----
  {
    const u16* hp = hb + (size_t)srcv * HH;
    bf16x8 af[8];
    #pragma unroll
    for (int kc = 0; kc < 8; ++kc)
      af[kc] = *(const bf16x8*)&hp[kc * 16 + hh * 8];
    #pragma unroll
    for (int kc = 0; kc < 8; ++kc) {
      const u16* bp = ew1c + ((8 + kc) * 4) * 512 + l * 8;
      #pragma unroll
      for (int nt = 0; nt < 4; ++nt) {
        bf16x8 b = *(const bf16x8*)(bp + nt * 512);
        acc[nt] = __builtin_amdgcn_mfma_f32_32x32x16_bf16(af[kc], b, acc[nt], 0, 0, 0);
      }
    }
  }
  // ---- GEMM1 phase attr+rbf (feat k 256..303, pre-marshalled tail) ----
  {
    const u16* tp = tail + (size_t)(e0 + myrow) * 48;
    bf16x8 afr[3];
    #pragma unroll
    for (int c = 0; c < 3; ++c)
      afr[c] = *(const bf16x8*)&tp[c * 16 + hh * 8];
    #pragma unroll
    for (int kc = 0; kc < 3; ++kc) {
      const u16* bp = ew1c + ((16 + kc) * 4) * 512 + l * 8;
      #pragma unroll
      for (int nt = 0; nt < 4; ++nt) {
        bf16x8 b = *(const bf16x8*)(bp + nt * 512);
        acc[nt] = __builtin_amdgcn_mfma_f32_32x32x16_bf16(afr[kc], b, acc[nt], 0, 0, 0);
      }
    }
  }
  // ---- GEMM1 epilogue: relu(+eb1) -> h1_s (wave-private rows) ----
  #pragma unroll
  for (int nt = 0; nt < 4; ++nt) {
    float bb = eb1[nt * 32 + l31];
    #pragma unroll
    for (int i = 0; i < 16; ++i) {
      float v = acc[nt][i] + bb; v = v > 0.f ? v : 0.f;
      int row = (i & 3) + 8 * (i >> 2) + 4 * hh;
      h1_s[(w * 32 + row) * MSTR + nt * 32 + l31] = f2b(v);
    }
  }

  // ---- GEMM2: A = h1 (own band, no barrier), B = ew2c ----
  bf16x8 a2[8];
  #pragma unroll
  for (int kc = 0; kc < 8; ++kc)
    a2[kc] = *(const bf16x8*)&h1_s[myrow * MSTR + kc * 16 + hh * 8];
  #pragma unroll
  for (int nt = 0; nt < 4; ++nt)
    #pragma unroll
    for (int i = 0; i < 16; ++i) acc[nt][i] = 0.f;
  #pragma unroll
  for (int kc = 0; kc < 8; ++kc) {
    const u16* bp = ew2c + (kc * 4) * 512 + l * 8;
    #pragma unroll
    for (int nt = 0; nt < 4; ++nt) {
      bf16x8 b = *(const bf16x8*)(bp + nt * 512);
      acc[nt] = __builtin_amdgcn_mfma_f32_32x32x16_bf16(a2[kc], b, acc[nt], 0, 0, 0);
    }
  }
  // ---- GEMM2 epilogue: mij = relu(+eb2) -> h1_s overlay; eij partials ----
  float p[16];
  #pragma unroll
  for (int i = 0; i < 16; ++i) p[i] = 0.f;
  #pragma unroll
  for (int nt = 0; nt < 4; ++nt) {
    float bb = eb2[nt * 32 + l31];
    float iw = inf_w[nt * 32 + l31];
    #pragma unroll
    for (int i = 0; i < 16; ++i) {
      float v = acc[nt][i] + bb; v = v > 0.f ? v : 0.f;
      p[i] += v * iw;
      int row = (i & 3) + 8 * (i >> 2) + 4 * hh;
      h1_s[(w * 32 + row) * MSTR + nt * 32 + l31] = f2b(v);
    }
  }
  // eij: reduce over 32 cols (xor, width 32), sigmoid
  {
    float ib = inf_b[0];
    #pragma unroll
    for (int m = 1; m < 32; m <<= 1)
      #pragma unroll
      for (int i = 0; i < 16; ++i) p[i] += __shfl_xor(p[i], m, 32);
    #pragma unroll
    for (int i = 0; i < 16; ++i)
      p[i] = 1.0f / (1.0f + __expf(-(p[i] + ib)));   // p = eij per row-slot
  }

  // ---- GEMM3: A = mij (own band), B = xw1c ----
  bf16x8 a3[8];
  #pragma unroll
  for (int kc = 0; kc < 8; ++kc)
    a3[kc] = *(const bf16x8*)&h1_s[myrow * MSTR + kc * 16 + hh * 8];
  #pragma unroll
  for (int nt = 0; nt < 4; ++nt)
    #pragma unroll
    for (int i = 0; i < 16; ++i) acc[nt][i] = 0.f;
  #pragma unroll
  for (int kc = 0; kc < 8; ++kc) {
    const u16* bp = xw1c + (kc * 4) * 512 + l * 8;
    #pragma unroll
    for (int nt = 0; nt < 4; ++nt) {
      bf16x8 b = *(const bf16x8*)(bp + nt * 512);
      acc[nt] = __builtin_amdgcn_mfma_f32_32x32x16_bf16(a3[kc], b, acc[nt], 0, 0, 0);
    }
  }
  // ---- xg = relu(+xb1) @ xw2 + xb2, reduced over cols ----
  float p2[16];
  #pragma unroll
  for (int i = 0; i < 16; ++i) p2[i] = 0.f;
  #pragma unroll
  for (int nt = 0; nt < 4; ++nt) {
    float bb = xb1[nt * 32 + l31];
    float xv = xw2[nt * 32 + l31];
    #pragma unroll
    for (int i = 0; i < 16; ++i) {
      float v = acc[nt][i] + bb; v = v > 0.f ? v : 0.f;
      p2[i] += v * xv;
    }
  }
  {
    float xb2_0 = xb2[0];
    #pragma unroll
    for (int m = 1; m < 32; m <<= 1)
      #pragma unroll
      for (int i = 0; i < 16; ++i) p2[i] += __shfl_xor(p2[i], m, 32);
    #pragma unroll
    for (int i = 0; i < 16; ++i) p2[i] += xb2_0;
  }

  // ---- atomics last: dx then mi (fire-and-forget, drained at endpgm) ----
  if (l31 < 3) {
    #pragma unroll
    for (int i = 0; i < 16; ++i) {
      int row = (i & 3) + 8 * (i >> 2) + 4 * hh;
      int gr = w * 32 + row;
      float rv = ((const float*)&relx_s[gr])[l31];
      atomicAdd(&dx[(size_t)dst_s[gr] * 3 + l31], rv * p2[i]);
    }
  }
  if ((l31 & 1) == 0) {
    #pragma unroll
    for (int nt = 0; nt < 4; ++nt) {
      #pragma unroll
      for (int i = 0; i < 16; ++i) {
        int row = (i & 3) + 8 * (i >> 2) + 4 * hh;
        int gr = w * 32 + row;
        unsigned int pr = *(const unsigned int*)&h1_s[gr * MSTR + nt * 32 + l31];
        float v0 = b2f(pr & 0xffffu) * p[i];
        float v1 = b2f(pr >> 16) * p[i];
        unsigned int packed = (unsigned int)f2b(v0) | ((unsigned int)f2b(v1) << 16);
        pk_atomic_bf16(mi + (size_t)dst_s[gr] * HH + nt * 32 + l31, packed);
      }
    }
  }
}

// ---------------------------------------------------------------------------
// node kernel: 16 rows/block, 1250 blocks; waves split N. h read via hb
// (bf16, direct loads). out = relu([mi,h]@nw1+nb1)@nw2+nb2 ; x_out = x+dx/E.
// ---------------------------------------------------------------------------
__global__ __launch_bounds__(256, 6) void node_kernel(
    const u16* __restrict__ hb, const float* __restrict__ x,
    const u16* __restrict__ nw1c, const float* __restrict__ nb1,
    const u16* __restrict__ nw2c, const float* __restrict__ nb2,
    const u16* __restrict__ mi, const float* __restrict__ dx,
    float* __restrict__ out) {
  __shared__ u16 h1_s[16 * MSTR];

  const int t   = threadIdx.x;
  const int w   = t >> 6;
  const int l   = t & 63;
  const int l15 = l & 15;
  const int q   = l >> 4;
  const int r0  = blockIdx.x * 16;
  const int gr  = r0 + l15;

  const u16* mp = mi + (size_t)gr * HH;
  const u16* hp = hb + (size_t)gr * HH;
  bf16x8 afrag[8];
  #pragma unroll
  for (int c = 0; c < 4; ++c) {
    afrag[c]     = *(const bf16x8*)&mp[c * 32 + q * 8];
    afrag[4 + c] = *(const bf16x8*)&hp[c * 32 + q * 8];
  }

  f32x4 acc[2];
  acc[0] = (f32x4){0.f, 0.f, 0.f, 0.f};
  acc[1] = (f32x4){0.f, 0.f, 0.f, 0.f};
  #pragma unroll
  for (int kc = 0; kc < 8; ++kc) {
    const u16* bp = nw1c + (kc << 12) + l * 8;
    #pragma unroll
    for (int i = 0; i < 2; ++i) {
      bf16x8 b = *(const bf16x8*)(bp + (2 * w + i) * 512);
      acc[i] = __builtin_amdgcn_mfma_f32_16x16x32_bf16(afrag[kc], b, acc[i], 0, 0, 0);
    }
  }
  #pragma unroll
  for (int i = 0; i < 2; ++i) {
    int nt = 2 * w + i;
    float b1 = nb1[nt * 16 + l15];
    #pragma unroll
    for (int r = 0; r < 4; ++r) {
      float v = acc[i][r] + b1; v = v > 0.f ? v : 0.f;
      h1_s[(q * 4 + r) * MSTR + nt * 16 + l15] = f2b(v);
    }
  }
  __syncthreads();

  bf16x8 a2[4];
  #pragma unroll
  for (int kc = 0; kc < 4; ++kc)
    a2[kc] = *(const bf16x8*)&h1_s[l15 * MSTR + kc * 32 + q * 8];
  acc[0] = (f32x4){0.f, 0.f, 0.f, 0.f};
  acc[1] = (f32x4){0.f, 0.f, 0.f, 0.f};
  #pragma unroll
  for (int kc = 0; kc < 4; ++kc) {
    const u16* bp = nw2c + (kc << 12) + l * 8;
    #pragma unroll
    for (int i = 0; i < 2; ++i) {
      bf16x8 b = *(const bf16x8*)(bp + (2 * w + i) * 512);
      acc[i] = __builtin_amdgcn_mfma_f32_16x16x32_bf16(a2[kc], b, acc[i], 0, 0, 0);
    }
  }
  #pragma unroll
  for (int i = 0; i < 2; ++i) {
    int nt = 2 * w + i;
    float b2 = nb2[nt * 16 + l15];
    #pragma unroll
    for (int r = 0; r < 4; ++r)
      out[(size_t)(r0 + q * 4 + r) * HH + nt * 16 + l15] = acc[i][r] + b2;
  }
  if (t < 48) {
    int rr = t / 3, dim = t % 3;
    int gr2 = r0 + rr;
    out[(size_t)NN * HH + (size_t)gr2 * 3 + dim] =
        x[(size_t)gr2 * 3 + dim] + dx[(size_t)gr2 * 3 + dim] * (1.0f / (float)EE);
  }
}

// ---------------------------------------------------------------------------
// launch
// ---------------------------------------------------------------------------
extern "C" void kernel_launch(void* const* d_in, const int* in_sizes, int n_in,
                              void* d_out, int out_size, void* d_ws, size_t ws_size,
                              hipStream_t stream) {
  const float* h         = (const float*)d_in[0];
  const float* x         = (const float*)d_in[1];
  const float* edge_attr = (const float*)d_in[2];
  const float* ew1 = (const float*)d_in[3];
  const float* eb1 = (const float*)d_in[4];
  const float* ew2 = (const float*)d_in[5];
  const float* eb2 = (const float*)d_in[6];
  const float* inf_w = (const float*)d_in[7];
  const float* inf_b = (const float*)d_in[8];
  const float* nw1 = (const float*)d_in[9];
  const float* nb1 = (const float*)d_in[10];
  const float* nw2 = (const float*)d_in[11];
  const float* nb2 = (const float*)d_in[12];
  const float* xw1 = (const float*)d_in[13];
  const float* xb1 = (const float*)d_in[14];
  const float* xw2 = (const float*)d_in[15];
  const float* xb2 = (const float*)d_in[16];
  const int* edge_index = (const int*)d_in[17];
  float* out = (float*)d_out;

  char* wsb = (char*)d_ws;
  u16*    ew1c  = (u16*)(wsb + 0);           //   81920 B (32-pack)
  u16*    ew2c  = (u16*)(wsb + 81920);       //   32768 B (32-pack)
  u16*    xw1c  = (u16*)(wsb + 114688);      //   32768 B (32-pack)
  u16*    nw1c  = (u16*)(wsb + 147456);      //   65536 B (16-pack)
  u16*    nw2c  = (u16*)(wsb + 212992);      //   32768 B (16-pack)
  u16*    mi    = (u16*)(wsb + 245760);      //  5120000 B (bf16)
  float*  dx    = (float*)(wsb + 5365760);   //   240000 B
  u16*    hb    = (u16*)(wsb + 5605760);     //  5120000 B (bf16 h)
  float4* relx4 = (float4*)(wsb + 10725760); //  5120000 B
  u16*    tail  = (u16*)(wsb + 15845760);    // 30720000 B -> total 46565760

  // prep zeroes mi+dx and converts h -> hb (no separate memset dispatch)
  prep_kernel<<<480, 256, 0, stream>>>(
      h, ew1, ew2, xw1, nw1, nw2, ew1c, ew2c, xw1c, nw1c, nw2c,
      (float4*)(wsb + 245760), hb);

  edge_prep_kernel<<<EE / 256, 256, 0, stream>>>(
      x, edge_attr, edge_index, relx4, tail);

  edge_kernel<<<EE / 128, 256, 0, stream>>>(
      hb, ew1c, eb1, ew2c, eb2, inf_w, inf_b,
      xw1c, xb1, xw2, xb2, edge_index, relx4, tail, mi, dx);

  node_kernel<<<NN / 16, 256, 0, stream>>>(
      hb, x, nw1c, nb1, nw2c, nb2, mi, dx, out);
}

// Round 11
// 270.544 us; speedup vs baseline: 1.3862x; 1.3862x over previous
//
#include <hip/hip_runtime.h>
#include <stdint.h>
#include <math.h>

// Problem constants
#define NN   20000
#define EE   320000
#define HH   128
#define MSTR 136            // h1/mij LDS row stride (u16)

typedef __attribute__((ext_vector_type(8)))  short          bf16x8;
typedef __attribute__((ext_vector_type(4)))  float          f32x4;
typedef __attribute__((ext_vector_type(16))) float          f32x16;
typedef unsigned short u16;

// fp32 -> bf16 round-to-nearest-even
__device__ __forceinline__ u16 f2b(float f) {
  union { float f; unsigned int u; } v; v.f = f;
  return (u16)((v.u + 0x7fffu + ((v.u >> 16) & 1u)) >> 16);
}
__device__ __forceinline__ float b2f(unsigned int x) {
  union { float f; unsigned int u; } v; v.u = x << 16;
  return v.f;
}
__device__ __forceinline__ bf16x8 cvt8(float4 a, float4 b) {
  bf16x8 r;
  r[0] = (short)f2b(a.x); r[1] = (short)f2b(a.y);
  r[2] = (short)f2b(a.z); r[3] = (short)f2b(a.w);
  r[4] = (short)f2b(b.x); r[5] = (short)f2b(b.y);
  r[6] = (short)f2b(b.z); r[7] = (short)f2b(b.w);
  return r;
}
__device__ __forceinline__ bf16x8 pack8(const float* v) {
  bf16x8 r;
  #pragma unroll
  for (int j = 0; j < 8; ++j) r[j] = (short)f2b(v[j]);
  return r;
}

// packed bf16x2 atomic add (CDNA4 global_atomic_pk_add_bf16), fire-and-forget
__device__ __forceinline__ void pk_atomic_bf16(u16* addr, unsigned int data) {
  asm volatile("global_atomic_pk_add_bf16 %0, %1, off"
               :
               : "v"((unsigned long long)(uintptr_t)addr), "v"(data)
               : "memory");
}

// ---------------------------------------------------------------------------
// prep: (a) zero mi+dx, (b) h -> bf16 (hb, used by node_kernel only —
// edge keeps fp32 h: R10 showed the edge-side cvt VALU is free latency filler),
// (c) pack weights to bf16.
// 32-style (edge GEMMs, mfma 32x32x16): n = nt*32+(l&31), k = kc*16+(l>>5)*8+j
// 16-style (node GEMMs, mfma 16x16x32): n = nt*16+(l&15), k = kc*32+(l>>4)*8+j
// ew1 K-rows permuted to feat order (hi | hj | attr+rbf | pad).
// ---------------------------------------------------------------------------
__global__ void prep_kernel(const float* __restrict__ h,
                            const float* __restrict__ ew1, const float* __restrict__ ew2,
                            const float* __restrict__ xw1, const float* __restrict__ nw1,
                            const float* __restrict__ nw2,
                            u16* __restrict__ ew1c, u16* __restrict__ ew2c,
                            u16* __restrict__ xw1c, u16* __restrict__ nw1c,
                            u16* __restrict__ nw2c, float4* __restrict__ zbase,
                            u16* __restrict__ hb) {
  int idx = blockIdx.x * 256 + threadIdx.x;

  // zero mi (bf16, 5120000 B) + dx (240000 B) = 335000 float4s
  float4 z4 = {0.f, 0.f, 0.f, 0.f};
  #pragma unroll
  for (int i = 0; i < 3; ++i) {
    int j = idx + i * 122880;
    if (j < 335000) zbase[j] = z4;
  }
  // h -> bf16: 2,560,000 elems = 320,000 chunks of 8
  #pragma unroll
  for (int i = 0; i < 3; ++i) {
    int c = idx + i * 122880;
    if (c < 320000) {
      float4 a = *(const float4*)&h[(size_t)c * 8];
      float4 b = *(const float4*)&h[(size_t)c * 8 + 4];
      *(bf16x8*)&hb[(size_t)c * 8] = cvt8(a, b);
    }
  }

  int i2, style;
  u16* dst;
  const float* src;
  if (idx < 40960)       { i2 = idx;          dst = ew1c; src = ew1; style = 1; }
  else if (idx < 57344)  { i2 = idx - 40960;  dst = ew2c; src = ew2; style = 1; }
  else if (idx < 73728)  { i2 = idx - 57344;  dst = xw1c; src = xw1; style = 1; }
  else if (idx < 106496) { i2 = idx - 73728;  dst = nw1c; src = nw1; style = 0; }
  else if (idx < 122880) { i2 = idx - 106496; dst = nw2c; src = nw2; style = 0; }
  else return;

  int n, k;
  if (style) {
    int kc = i2 >> 11, rem = i2 & 2047, nt = rem >> 9, rem2 = rem & 511;
    int l = rem2 >> 3, j = rem2 & 7;
    n = nt * 32 + (l & 31);
    k = kc * 16 + (l >> 5) * 8 + j;
  } else {
    int kc = i2 >> 12, rem = i2 & 4095, nt = rem >> 9, rem2 = rem & 511;
    int l = rem2 >> 3, j = rem2 & 7;
    n = nt * 16 + (l & 15);
    k = kc * 32 + (l >> 4) * 8 + j;
  }
  float v;
  if (dst == ew1c) {
    if (k < 256)      v = src[(k + 48) * HH + n];   // hi|hj block
    else if (k < 304) v = src[(k - 256) * HH + n];  // attr|rbf block
    else              v = 0.0f;                     // pad (kc 19, unused)
  } else {
    v = src[k * HH + n];
  }
  dst[i2] = f2b(v);
}

// ---------------------------------------------------------------------------
// edge kernel (R9 body verbatim — best measured 163 us): 128 edges/block,
// 4 waves, wave owns 32 rows x 128 cols. mfma 32x32x16, one barrier,
// in-kernel rbf/attr marshalling (co-issued VALU = free latency filler),
// atomics last. bounds(256,3): no clamp (needs ~148 unified regs: 84 arch
// + 64 AGPR; R8 showed (256,4) clamps at 128 and spills).
// ---------------------------------------------------------------------------
__global__ __launch_bounds__(256, 3) void edge_kernel(
    const float* __restrict__ h, const float* __restrict__ x,
    const float* __restrict__ edge_attr,
    const u16* __restrict__ ew1c, const float* __restrict__ eb1,
    const u16* __restrict__ ew2c, const float* __restrict__ eb2,
    const float* __restrict__ inf_w, const float* __restrict__ inf_b,
    const u16* __restrict__ xw1c, const float* __restrict__ xb1,
    const float* __restrict__ xw2, const float* __restrict__ xb2,
    const int* __restrict__ edge_index,
    u16* __restrict__ mi, float* __restrict__ dx) {
  __shared__ u16 h1_s[128 * MSTR];     // 34816 B: GEMM1 out, then mij overlay
  __shared__ float relx_s[128][4];     //  2048 B
  __shared__ int dst_s[128];           //   512 B
  __shared__ int src_s[128];           //   512 B

  const int t   = threadIdx.x;
  const int w   = t >> 6;
  const int l   = t & 63;
  const int l31 = l & 31;
  const int hh  = l >> 5;              // k-half
  const int e0  = blockIdx.x * 128;
  const int myrow = w * 32 + l31;      // local row 0..127

  // ---- phase A: indices + rel_x + |rel_x| (the only barrier) ----
  if (t < 128) {
    int d = edge_index[e0 + t];
    int s = edge_index[EE + e0 + t];
    dst_s[t] = d; src_s[t] = s;
    float rx = x[d * 3 + 0] - x[s * 3 + 0];
    float ry = x[d * 3 + 1] - x[s * 3 + 1];
    float rz = x[d * 3 + 2] - x[s * 3 + 2];
    relx_s[t][0] = rx; relx_s[t][1] = ry; relx_s[t][2] = rz;
    relx_s[t][3] = sqrtf(rx * rx + ry * ry + rz * rz);
  }
  __syncthreads();

  const int dstv = dst_s[myrow];
  const int srcv = src_s[myrow];

  f32x16 acc[4];
  #pragma unroll
  for (int nt = 0; nt < 4; ++nt)
    #pragma unroll
    for (int i = 0; i < 16; ++i) acc[nt][i] = 0.f;

  // ---- GEMM1 phase hi (feat k 0..127 = h[dst]) ----
  {
    const float* hp = h + (size_t)dstv * HH;
    bf16x8 af[8];
    #pragma unroll
    for (int kc = 0; kc < 8; ++kc) {
      float4 a0 = *(const float4*)&hp[kc * 16 + hh * 8];
      float4 a1 = *(const float4*)&hp[kc * 16 + hh * 8 + 4];
      af[kc] = cvt8(a0, a1);
    }
    #pragma unroll
    for (int kc = 0; kc < 8; ++kc) {
      const u16* bp = ew1c + (kc * 4) * 512 + l * 8;
      #pragma unroll
      for (int nt = 0; nt < 4; ++nt) {
        bf16x8 b = *(const bf16x8*)(bp + nt * 512);
        acc[nt] = __builtin_amdgcn_mfma_f32_32x32x16_bf16(af[kc], b, acc[nt], 0, 0, 0);
      }
    }
  }
  // ---- GEMM1 phase hj (feat k 128..255 = h[src]) ----
  {
    const float* hp = h + (size_t)srcv * HH;
    bf16x8 af[8];
    #pragma unroll
    for (int kc = 0; kc < 8; ++kc) {
      float4 a0 = *(const float4*)&hp[kc * 16 + hh * 8];
      float4 a1 = *(const float4*)&hp[kc * 16 + hh * 8 + 4];
      af[kc] = cvt8(a0, a1);
    }
    #pragma unroll
    for (int kc = 0; kc < 8; ++kc) {
      const u16* bp = ew1c + ((8 + kc) * 4) * 512 + l * 8;
      #pragma unroll
      for (int nt = 0; nt < 4; ++nt) {
        bf16x8 b = *(const bf16x8*)(bp + nt * 512);
        acc[nt] = __builtin_amdgcn_mfma_f32_32x32x16_bf16(af[kc], b, acc[nt], 0, 0, 0);
      }
    }
  }
  // ---- GEMM1 phase attr+rbf (feat k 256..303; kc 16..18) ----
  {
    const float step  = 100.0f / 19.0f;
    const float coeff = -0.5f / (step * step);
    const float dn    = relx_s[myrow][3];
    const float* ap   = edge_attr + (size_t)(e0 + myrow) * 28;
    float v0[8], v1[8], v2[8];
    if (hh == 0) {
      float4 a0 = *(const float4*)&ap[0],  a1 = *(const float4*)&ap[4];
      float4 a2 = *(const float4*)&ap[16], a3 = *(const float4*)&ap[20];
      v0[0]=a0.x; v0[1]=a0.y; v0[2]=a0.z; v0[3]=a0.w;
      v0[4]=a1.x; v0[5]=a1.y; v0[6]=a1.z; v0[7]=a1.w;
      v1[0]=a2.x; v1[1]=a2.y; v1[2]=a2.z; v1[3]=a2.w;
      v1[4]=a3.x; v1[5]=a3.y; v1[6]=a3.z; v1[7]=a3.w;
      #pragma unroll
      for (int j = 0; j < 8; ++j) {           // rbf 4..11
        float dd = dn - (float)(4 + j) * step;
        v2[j] = __expf(coeff * dd * dd);
      }
    } else {
      float4 a0 = *(const float4*)&ap[8],  a1 = *(const float4*)&ap[12];
      float4 a2 = *(const float4*)&ap[24];
      v0[0]=a0.x; v0[1]=a0.y; v0[2]=a0.z; v0[3]=a0.w;
      v0[4]=a1.x; v0[5]=a1.y; v0[6]=a1.z; v0[7]=a1.w;
      v1[0]=a2.x; v1[1]=a2.y; v1[2]=a2.z; v1[3]=a2.w;
      #pragma unroll
      for (int j = 0; j < 4; ++j) {           // rbf 0..3
        float dd = dn - (float)j * step;
        v1[4 + j] = __expf(coeff * dd * dd);
      }
      #pragma unroll
      for (int j = 0; j < 8; ++j) {           // rbf 12..19
        float dd = dn - (float)(12 + j) * step;
        v2[j] = __expf(coeff * dd * dd);
      }
    }
    bf16x8 afr[3];
    afr[0] = pack8(v0); afr[1] = pack8(v1); afr[2] = pack8(v2);
    #pragma unroll
    for (int kc = 0; kc < 3; ++kc) {
      const u16* bp = ew1c + ((16 + kc) * 4) * 512 + l * 8;
      #pragma unroll
      for (int nt = 0; nt < 4; ++nt) {
        bf16x8 b = *(const bf16x8*)(bp + nt * 512);
        acc[nt] = __builtin_amdgcn_mfma_f32_32x32x16_bf16(afr[kc], b, acc[nt], 0, 0, 0);
      }
    }
  }
  // ---- GEMM1 epilogue: relu(+eb1) -> h1_s (wave-private rows) ----
  #pragma unroll
  for (int nt = 0; nt < 4; ++nt) {
    float bb = eb1[nt * 32 + l31];
    #pragma unroll
    for (int i = 0; i < 16; ++i) {
      float v = acc[nt][i] + bb; v = v > 0.f ? v : 0.f;
      int row = (i & 3) + 8 * (i >> 2) + 4 * hh;
      h1_s[(w * 32 + row) * MSTR + nt * 32 + l31] = f2b(v);
    }
  }

  // ---- GEMM2: A = h1 (own band, no barrier), B = ew2c ----
  bf16x8 a2[8];
  #pragma unroll
  for (int kc = 0; kc < 8; ++kc)
    a2[kc] = *(const bf16x8*)&h1_s[myrow * MSTR + kc * 16 + hh * 8];
  #pragma unroll
  for (int nt = 0; nt < 4; ++nt)
    #pragma unroll
    for (int i = 0; i < 16; ++i) acc[nt][i] = 0.f;
  #pragma unroll
  for (int kc = 0; kc < 8; ++kc) {
    const u16* bp = ew2c + (kc * 4) * 512 + l * 8;
    #pragma unroll
    for (int nt = 0; nt < 4; ++nt) {
      bf16x8 b = *(const bf16x8*)(bp + nt * 512);
      acc[nt] = __builtin_amdgcn_mfma_f32_32x32x16_bf16(a2[kc], b, acc[nt], 0, 0, 0);
    }
  }
  // ---- GEMM2 epilogue: mij = relu(+eb2) -> h1_s overlay; eij partials ----
  float p[16];
  #pragma unroll
  for (int i = 0; i < 16; ++i) p[i] = 0.f;
  #pragma unroll
  for (int nt = 0; nt < 4; ++nt) {
    float bb = eb2[nt * 32 + l31];
    float iw = inf_w[nt * 32 + l31];
    #pragma unroll
    for (int i = 0; i < 16; ++i) {
      float v = acc[nt][i] + bb; v = v > 0.f ? v : 0.f;
      p[i] += v * iw;
      int row = (i & 3) + 8 * (i >> 2) + 4 * hh;
      h1_s[(w * 32 + row) * MSTR + nt * 32 + l31] = f2b(v);
    }
  }
  // eij: reduce over 32 cols (xor, width 32), sigmoid
  {
    float ib = inf_b[0];
    #pragma unroll
    for (int m = 1; m < 32; m <<= 1)
      #pragma unroll
      for (int i = 0; i < 16; ++i) p[i] += __shfl_xor(p[i], m, 32);
    #pragma unroll
    for (int i = 0; i < 16; ++i)
      p[i] = 1.0f / (1.0f + __expf(-(p[i] + ib)));   // p = eij per row-slot
  }

  // ---- GEMM3: A = mij (own band), B = xw1c ----
  bf16x8 a3[8];
  #pragma unroll
  for (int kc = 0; kc < 8; ++kc)
    a3[kc] = *(const bf16x8*)&h1_s[myrow * MSTR + kc * 16 + hh * 8];
  #pragma unroll
  for (int nt = 0; nt < 4; ++nt)
    #pragma unroll
    for (int i = 0; i < 16; ++i) acc[nt][i] = 0.f;
  #pragma unroll
  for (int kc = 0; kc < 8; ++kc) {
    const u16* bp = xw1c + (kc * 4) * 512 + l * 8;
    #pragma unroll
    for (int nt = 0; nt < 4; ++nt) {
      bf16x8 b = *(const bf16x8*)(bp + nt * 512);
      acc[nt] = __builtin_amdgcn_mfma_f32_32x32x16_bf16(a3[kc], b, acc[nt], 0, 0, 0);
    }
  }
  // ---- xg = relu(+xb1) @ xw2 + xb2, reduced over cols ----
  float p2[16];
  #pragma unroll
  for (int i = 0; i < 16; ++i) p2[i] = 0.f;
  #pragma unroll
  for (int nt = 0; nt < 4; ++nt) {
    float bb = xb1[nt * 32 + l31];
    float xv = xw2[nt * 32 + l31];
    #pragma unroll
    for (int i = 0; i < 16; ++i) {
      float v = acc[nt][i] + bb; v = v > 0.f ? v : 0.f;
      p2[i] += v * xv;
    }
  }
  {
    float xb2_0 = xb2[0];
    #pragma unroll
    for (int m = 1; m < 32; m <<= 1)
      #pragma unroll
      for (int i = 0; i < 16; ++i) p2[i] += __shfl_xor(p2[i], m, 32);
    #pragma unroll
    for (int i = 0; i < 16; ++i) p2[i] += xb2_0;
  }

  // ---- atomics last: dx then mi (fire-and-forget, drained at endpgm) ----
  if (l31 < 3) {
    #pragma unroll
    for (int i = 0; i < 16; ++i) {
      int row = (i & 3) + 8 * (i >> 2) + 4 * hh;
      int gr = w * 32 + row;
      atomicAdd(&dx[(size_t)dst_s[gr] * 3 + l31], relx_s[gr][l31] * p2[i]);
    }
  }
  if ((l31 & 1) == 0) {
    #pragma unroll
    for (int nt = 0; nt < 4; ++nt) {
      #pragma unroll
      for (int i = 0; i < 16; ++i) {
        int row = (i & 3) + 8 * (i >> 2) + 4 * hh;
        int gr = w * 32 + row;
        unsigned int pr = *(const unsigned int*)&h1_s[gr * MSTR + nt * 32 + l31];
        float v0 = b2f(pr & 0xffffu) * p[i];
        float v1 = b2f(pr >> 16) * p[i];
        unsigned int packed = (unsigned int)f2b(v0) | ((unsigned int)f2b(v1) << 16);
        pk_atomic_bf16(mi + (size_t)dst_s[gr] * HH + nt * 32 + l31, packed);
      }
    }
  }
}

// ---------------------------------------------------------------------------
// node kernel: 16 rows/block, 1250 blocks; waves split N. h read via hb
// (bf16, direct contiguous loads — safe here, unlike edge's gathers).
// out = relu([mi,h]@nw1+nb1)@nw2+nb2 ; x_out = x + dx/E.  16x16x32 MFMA.
// ---------------------------------------------------------------------------
__global__ __launch_bounds__(256, 6) void node_kernel(
    const u16* __restrict__ hb, const float* __restrict__ x,
    const u16* __restrict__ nw1c, const float* __restrict__ nb1,
    const u16* __restrict__ nw2c, const float* __restrict__ nb2,
    const u16* __restrict__ mi, const float* __restrict__ dx,
    float* __restrict__ out) {
  __shared__ u16 h1_s[16 * MSTR];

  const int t   = threadIdx.x;
  const int w   = t >> 6;
  const int l   = t & 63;
  const int l15 = l & 15;
  const int q   = l >> 4;
  const int r0  = blockIdx.x * 16;
  const int gr  = r0 + l15;

  const u16* mp = mi + (size_t)gr * HH;
  const u16* hp = hb + (size_t)gr * HH;
  bf16x8 afrag[8];
  #pragma unroll
  for (int c = 0; c < 4; ++c) {
    afrag[c]     = *(const bf16x8*)&mp[c * 32 + q * 8];
    afrag[4 + c] = *(const bf16x8*)&hp[c * 32 + q * 8];
  }

  f32x4 acc[2];
  acc[0] = (f32x4){0.f, 0.f, 0.f, 0.f};
  acc[1] = (f32x4){0.f, 0.f, 0.f, 0.f};
  #pragma unroll
  for (int kc = 0; kc < 8; ++kc) {
    const u16* bp = nw1c + (kc << 12) + l * 8;
    #pragma unroll
    for (int i = 0; i < 2; ++i) {
      bf16x8 b = *(const bf16x8*)(bp + (2 * w + i) * 512);
      acc[i] = __builtin_amdgcn_mfma_f32_16x16x32_bf16(afrag[kc], b, acc[i], 0, 0, 0);
    }
  }
  #pragma unroll
  for (int i = 0; i < 2; ++i) {
    int nt = 2 * w + i;
    float b1 = nb1[nt * 16 + l15];
    #pragma unroll
    for (int r = 0; r < 4; ++r) {
      float v = acc[i][r] + b1; v = v > 0.f ? v : 0.f;
      h1_s[(q * 4 + r) * MSTR + nt * 16 + l15] = f2b(v);
    }
  }
  __syncthreads();

  bf16x8 a2[4];
  #pragma unroll
  for (int kc = 0; kc < 4; ++kc)
    a2[kc] = *(const bf16x8*)&h1_s[l15 * MSTR + kc * 32 + q * 8];
  acc[0] = (f32x4){0.f, 0.f, 0.f, 0.f};
  acc[1] = (f32x4){0.f, 0.f, 0.f, 0.f};
  #pragma unroll
  for (int kc = 0; kc < 4; ++kc) {
    const u16* bp = nw2c + (kc << 12) + l * 8;
    #pragma unroll
    for (int i = 0; i < 2; ++i) {
      bf16x8 b = *(const bf16x8*)(bp + (2 * w + i) * 512);
      acc[i] = __builtin_amdgcn_mfma_f32_16x16x32_bf16(a2[kc], b, acc[i], 0, 0, 0);
    }
  }
  #pragma unroll
  for (int i = 0; i < 2; ++i) {
    int nt = 2 * w + i;
    float b2 = nb2[nt * 16 + l15];
    #pragma unroll
    for (int r = 0; r < 4; ++r)
      out[(size_t)(r0 + q * 4 + r) * HH + nt * 16 + l15] = acc[i][r] + b2;
  }
  if (t < 48) {
    int rr = t / 3, dim = t % 3;
    int gr2 = r0 + rr;
    out[(size_t)NN * HH + (size_t)gr2 * 3 + dim] =
        x[(size_t)gr2 * 3 + dim] + dx[(size_t)gr2 * 3 + dim] * (1.0f / (float)EE);
  }
}

// ---------------------------------------------------------------------------
// launch
// ---------------------------------------------------------------------------
extern "C" void kernel_launch(void* const* d_in, const int* in_sizes, int n_in,
                              void* d_out, int out_size, void* d_ws, size_t ws_size,
                              hipStream_t stream) {
  const float* h         = (const float*)d_in[0];
  const float* x         = (const float*)d_in[1];
  const float* edge_attr = (const float*)d_in[2];
  const float* ew1 = (const float*)d_in[3];
  const float* eb1 = (const float*)d_in[4];
  const float* ew2 = (const float*)d_in[5];
  const float* eb2 = (const float*)d_in[6];
  const float* inf_w = (const float*)d_in[7];
  const float* inf_b = (const float*)d_in[8];
  const float* nw1 = (const float*)d_in[9];
  const float* nb1 = (const float*)d_in[10];
  const float* nw2 = (const float*)d_in[11];
  const float* nb2 = (const float*)d_in[12];
  const float* xw1 = (const float*)d_in[13];
  const float* xb1 = (const float*)d_in[14];
  const float* xw2 = (const float*)d_in[15];
  const float* xb2 = (const float*)d_in[16];
  const int* edge_index = (const int*)d_in[17];
  float* out = (float*)d_out;

  char* wsb = (char*)d_ws;
  u16*   ew1c = (u16*)(wsb + 0);          //   81920 B (32-pack)
  u16*   ew2c = (u16*)(wsb + 81920);      //   32768 B (32-pack)
  u16*   xw1c = (u16*)(wsb + 114688);     //   32768 B (32-pack)
  u16*   nw1c = (u16*)(wsb + 147456);     //   65536 B (16-pack)
  u16*   nw2c = (u16*)(wsb + 212992);     //   32768 B (16-pack)
  u16*   mi   = (u16*)(wsb + 245760);     //  5120000 B (bf16)
  float* dx   = (float*)(wsb + 5365760);  //   240000 B
  u16*   hb   = (u16*)(wsb + 5605760);    //  5120000 B (bf16 h) -> 10725760

  // prep zeroes mi+dx and converts h -> hb (no separate memset dispatch)
  prep_kernel<<<480, 256, 0, stream>>>(
      h, ew1, ew2, xw1, nw1, nw2, ew1c, ew2c, xw1c, nw1c, nw2c,
      (float4*)(wsb + 245760), hb);

  edge_kernel<<<EE / 128, 256, 0, stream>>>(
      h, x, edge_attr, ew1c, eb1, ew2c, eb2, inf_w, inf_b,
      xw1c, xb1, xw2, xb2, edge_index, mi, dx);

  node_kernel<<<NN / 16, 256, 0, stream>>>(
      hb, x, nw1c, nb1, nw2c, nb2, mi, dx, out);
}